// Round 2
// baseline (571.949 us; speedup 1.0000x reference)
//
#include <hip/hip_runtime.h>
#include <hip/hip_bf16.h>

// Problem constants (N, K, C, CL, H fixed by the reference)
constexpr int Nn  = 1024;
constexpr int Kk  = 32;
constexpr int Cc  = 64;
constexpr int CLl = 128;

__device__ __forceinline__ float gelu_tanh(float v){
  float c = 0.7978845608028654f*(v + 0.044715f*v*v*v);
  return 0.5f*v*(1.f + tanhf(c));
}

// ---------------------------------------------------------------------------
// K0: A = local@Wa, B = local@Wb, inter = local@W_int + b_int  (all [N,64] f32)
// block = row i (64 threads = one output channel each)
// ---------------------------------------------------------------------------
__global__ __launch_bounds__(64) void k0(
    const float* __restrict__ local, const float* __restrict__ Wa,
    const float* __restrict__ Wb, const float* __restrict__ Wint,
    const float* __restrict__ b_int,
    float* __restrict__ A, float* __restrict__ B, float* __restrict__ inter){
  int i = blockIdx.x;
  int c = threadIdx.x;              // 0..63
  __shared__ float l[CLl];
  l[c]      = local[i*CLl + c];
  l[c + 64] = local[i*CLl + 64 + c];
  __syncthreads();
  float a = 0.f, b = 0.f, t = 0.f;
  #pragma unroll 4
  for(int d = 0; d < CLl; ++d){
    float ld = l[d];
    a = fmaf(ld, Wa[d*Cc + c], a);
    b = fmaf(ld, Wb[d*Cc + c], b);
    t = fmaf(ld, Wint[d*Cc + c], t);
  }
  A[i*Cc + c] = a;
  B[i*Cc + c] = b;
  inter[i*Cc + c] = t + b_int[c];
}

// ---------------------------------------------------------------------------
// K1: r1023[k][x] = (lp_row1023 @ W_right + b_right)[x],  qpart[k]
// Single block, 256 threads (8 threads per slot k).
// ---------------------------------------------------------------------------
__global__ __launch_bounds__(256) void k1(
    const float* __restrict__ pair, const float* __restrict__ pair_update,
    const int* __restrict__ neigh, const int* __restrict__ mask,
    const float* __restrict__ ln_g, const float* __restrict__ ln_b,
    const float* __restrict__ W_aug, const float* __restrict__ W_right,
    const float* __restrict__ b_right,
    const float* __restrict__ A, const float* __restrict__ B,
    float* __restrict__ r1023, int* __restrict__ qpart){
  const int i = Nn - 1;
  __shared__ float wA[4096];
  __shared__ float wR[2048];
  __shared__ float p [Kk][68];
  __shared__ float pu[Kk][68];
  __shared__ float lp[Kk][68];
  __shared__ int   nwS[Kk];
  __shared__ float ssum[Kk][9], ssq[Kk][9], stats[Kk][2];
  int tid = threadIdx.x;
  for(int idx = tid; idx < 4096; idx += 256) wA[idx] = W_aug[idx];
  for(int idx = tid; idx < 2048; idx += 256) wR[idx] = W_right[idx];
  if(tid < Kk){
    int n = neigh[i*Kk + tid];
    nwS[tid] = (n < 0) ? n + Nn : n;
    qpart[tid] = (n != -1 && mask[n] != 0) ? 1 : 0;
  }
  __syncthreads();
  int k = tid >> 3, s = tid & 7;
  {
    const float* prow = pair + ((size_t)i*Nn + nwS[k])*Cc + s*8;
    const float* pur  = pair_update + ((size_t)i*Kk + k)*Cc + s*8;
    const float* Ar = A + i*Cc + s*8;
    const float* Br = B + (size_t)nwS[k]*Cc + s*8;
    float ps = 0.f, ps2 = 0.f;
    for(int j = 0; j < 8; ++j){
      float v = prow[j];
      p[k][s*8 + j] = v; ps += v; ps2 += v*v;
      pu[k][s*8 + j] = pur[j] + Ar[j] + Br[j];
    }
    ssum[k][s] = ps; ssq[k][s] = ps2;
  }
  __syncthreads();
  if(s == 0){
    float m = 0.f, q = 0.f;
    for(int j = 0; j < 8; ++j){ m += ssum[k][j]; q += ssq[k][j]; }
    m *= (1.f/64.f); q *= (1.f/64.f);
    float var = fmaxf(q - m*m, 0.f);
    stats[k][0] = m; stats[k][1] = rsqrtf(var + 1e-5f);
  }
  __syncthreads();
  {
    float m = stats[k][0], r = stats[k][1];
    float acc[8];
    #pragma unroll
    for(int j = 0; j < 8; ++j){
      int c = s*8 + j;
      acc[j] = (p[k][c] - m)*r*ln_g[c] + ln_b[c];
    }
    for(int d = 0; d < 64; ++d){
      float pd = pu[k][d];
      #pragma unroll
      for(int j = 0; j < 8; ++j) acc[j] = fmaf(pd, wA[d*64 + s*8 + j], acc[j]);
    }
    #pragma unroll
    for(int j = 0; j < 8; ++j) lp[k][s*8 + j] = acc[j];
  }
  __syncthreads();
  {
    float acc[4] = {0.f,0.f,0.f,0.f};
    for(int d = 0; d < 64; ++d){
      float ld = lp[k][d];
      #pragma unroll
      for(int j = 0; j < 4; ++j) acc[j] = fmaf(ld, wR[d*32 + s*4 + j], acc[j]);
    }
    #pragma unroll
    for(int j = 0; j < 4; ++j)
      r1023[k*32 + s*4 + j] = acc[j] + b_right[s*4 + j];
  }
}

// ---------------------------------------------------------------------------
// Kcopy: out = pair (bit copy, f32), uint4 grid-stride
// ---------------------------------------------------------------------------
__global__ __launch_bounds__(256) void kcopy(
    const uint4* __restrict__ src, uint4* __restrict__ dst, int nvec){
  int idx = blockIdx.x*blockDim.x + threadIdx.x;
  int stride = gridDim.x*blockDim.x;
  for(; idx < nvec; idx += stride) dst[idx] = src[idx];
}

// ---------------------------------------------------------------------------
// K2a: per row i — gather + LN + lp = LN*g+b + pu@W_aug;
//      lin[i,k,:] = lp@W_lin + inter[i,:];  h[i,k,:] = lp@W_left + b_left + r1023[k]
// 256 threads: 8 threads per slot k; thread (k,s) owns cols s*8..s*8+7.
// ---------------------------------------------------------------------------
__global__ __launch_bounds__(256) void k2a(
    const float* __restrict__ pair, const float* __restrict__ pair_update,
    const int* __restrict__ neigh,
    const float* __restrict__ ln_g, const float* __restrict__ ln_b,
    const float* __restrict__ W_aug, const float* __restrict__ W_lin,
    const float* __restrict__ W_left, const float* __restrict__ b_left,
    const float* __restrict__ A, const float* __restrict__ B,
    const float* __restrict__ inter, const float* __restrict__ r1023,
    float* __restrict__ hG, float* __restrict__ linG){
  __shared__ float wA[4096];          // W_aug  [64][64]
  __shared__ float wL[4096];          // W_lin  [64][64]
  __shared__ float wF[2048];          // W_left [64][32]
  __shared__ float pbuf [Kk][68];     // pair raw -> (phase3 in-place) lp
  __shared__ float pubuf[Kk][68];     // pu
  __shared__ float AiS[64], InS[64];
  __shared__ float ssum[Kk][9], ssq[Kk][9], stats[Kk][2];
  __shared__ int nwS[Kk];

  int i   = blockIdx.x;
  int tid = threadIdx.x;
  int k   = tid >> 3, s = tid & 7;

  for(int idx = tid; idx < 4096; idx += 256) wA[idx] = W_aug[idx];
  for(int idx = tid; idx < 4096; idx += 256) wL[idx] = W_lin[idx];
  for(int idx = tid; idx < 2048; idx += 256) wF[idx] = W_left[idx];
  if(tid < Kk){
    int n = neigh[i*Kk + tid];
    nwS[tid] = (n < 0) ? n + Nn : n;
  }
  if(tid < 64){ AiS[tid] = A[i*Cc + tid]; InS[tid] = inter[i*Cc + tid]; }
  __syncthreads();

  // ---- gather pair row segments + build pu ----
  {
    const float4* p4 = (const float4*)(pair + ((size_t)i*Nn + nwS[k])*Cc) + s*2;
    float4 p0 = p4[0], p1 = p4[1];
    const float4* u4 = (const float4*)(pair_update + ((size_t)i*Kk + k)*Cc) + s*2;
    float4 u0 = u4[0], u1 = u4[1];
    const float4* Br = (const float4*)(B + (size_t)nwS[k]*Cc) + s*2;
    float4 b0 = Br[0], b1 = Br[1];
    float pf[8] = {p0.x,p0.y,p0.z,p0.w,p1.x,p1.y,p1.z,p1.w};
    float uf[8] = {u0.x,u0.y,u0.z,u0.w,u1.x,u1.y,u1.z,u1.w};
    float bv[8] = {b0.x,b0.y,b0.z,b0.w,b1.x,b1.y,b1.z,b1.w};
    float ps = 0.f, ps2 = 0.f;
    #pragma unroll
    for(int j = 0; j < 8; ++j){
      float v = pf[j];
      pbuf[k][s*8 + j] = v; ps += v; ps2 += v*v;
      pubuf[k][s*8 + j] = uf[j] + AiS[s*8 + j] + bv[j];
    }
    ssum[k][s] = ps; ssq[k][s] = ps2;
  }
  __syncthreads();

  // ---- LN stats ----
  if(s == 0){
    float m = 0.f, q = 0.f;
    for(int j = 0; j < 8; ++j){ m += ssum[k][j]; q += ssq[k][j]; }
    m *= (1.f/64.f); q *= (1.f/64.f);
    float var = fmaxf(q - m*m, 0.f);
    stats[k][0] = m; stats[k][1] = rsqrtf(var + 1e-5f);
  }
  __syncthreads();

  // ---- lp = LN(pair)*g+b + pu @ W_aug   (written in-place into pbuf) ----
  {
    float m = stats[k][0], r = stats[k][1];
    float acc[8];
    #pragma unroll
    for(int j = 0; j < 8; ++j){
      int c = s*8 + j;
      acc[j] = (pbuf[k][c] - m)*r*ln_g[c] + ln_b[c];
    }
    #pragma unroll 4
    for(int d = 0; d < 64; ++d){
      float pd = pubuf[k][d];
      #pragma unroll
      for(int j = 0; j < 8; ++j) acc[j] = fmaf(pd, wA[d*64 + s*8 + j], acc[j]);
    }
    #pragma unroll
    for(int j = 0; j < 8; ++j) pbuf[k][s*8 + j] = acc[j];
  }
  __syncthreads();

  // ---- lin = lp@W_lin + inter;  h = lp@W_left + b_left + r1023 ----
  {
    float accL[8] = {0,0,0,0,0,0,0,0};
    float accX[4] = {0,0,0,0};
    #pragma unroll 4
    for(int d = 0; d < 64; ++d){
      float ld = pbuf[k][d];
      #pragma unroll
      for(int j = 0; j < 8; ++j) accL[j] = fmaf(ld, wL[d*64 + s*8 + j], accL[j]);
      #pragma unroll
      for(int j = 0; j < 4; ++j) accX[j] = fmaf(ld, wF[d*32 + s*4 + j], accX[j]);
    }
    float4 rv = *(const float4*)(r1023 + k*32 + s*4);
    float rr[4] = {rv.x, rv.y, rv.z, rv.w};
    float* lo = linG + ((size_t)i*Kk + k)*Cc + s*8;
    #pragma unroll
    for(int j = 0; j < 8; ++j) lo[j] = accL[j] + InS[s*8 + j];
    float* ho = hG + ((size_t)i*Kk + k)*32 + s*4;
    #pragma unroll
    for(int j = 0; j < 4; ++j) ho[j] = accX[j] + b_left[s*4 + j] + rr[j];
  }
}

// ---------------------------------------------------------------------------
// K2b: per row i — V = gelu(h@W1)@W2, contrib = mul*V + lin, leader scatter-RMW
// ---------------------------------------------------------------------------
__global__ __launch_bounds__(256) void k2b(
    const float* __restrict__ pair, const int* __restrict__ neigh,
    const float* __restrict__ W1, const float* __restrict__ W2,
    const float* __restrict__ hG, const float* __restrict__ linG,
    const int* __restrict__ qpart,
    float* __restrict__ out){
  __shared__ float w1s[4096];         // W1 [32][128]
  __shared__ float w2s[8192];         // W2 [128][64]
  __shared__ float hbuf[Kk][36];
  __shared__ float cbuf[Kk][68];      // contrib
  __shared__ int nbS[Kk], nwS[Kk], quS[Kk], leadS[Kk];
  __shared__ int cminus;

  int i   = blockIdx.x;
  int tid = threadIdx.x;
  int k   = tid >> 3, s = tid & 7;

  for(int idx = tid; idx < 4096; idx += 256) w1s[idx] = W1[idx];
  for(int idx = tid; idx < 8192; idx += 256) w2s[idx] = W2[idx];
  for(int idx = tid; idx < 1024; idx += 256)
    hbuf[idx >> 5][idx & 31] = hG[(size_t)i*1024 + idx];
  if(tid < Kk){
    int n = neigh[i*Kk + tid];
    nbS[tid] = n;
    nwS[tid] = (n < 0) ? n + Nn : n;
    quS[tid] = qpart[tid];
  }
  __syncthreads();
  if(tid == 0){
    int c = 0;
    for(int kk = 0; kk < Kk; ++kk) c |= (nbS[kk] == -1);
    cminus = c;
  }

  // ---- g1 = gelu(h @ W1) -> registers (16 per thread: h-cols s*16..s*16+15) ----
  float gg[16];
  {
    float acc[16];
    #pragma unroll
    for(int j = 0; j < 16; ++j) acc[j] = 0.f;
    #pragma unroll 2
    for(int x = 0; x < 32; ++x){
      float hx = hbuf[k][x];
      #pragma unroll
      for(int j = 0; j < 16; ++j) acc[j] = fmaf(hx, w1s[x*128 + s*16 + j], acc[j]);
    }
    #pragma unroll
    for(int j = 0; j < 16; ++j) gg[j] = gelu_tanh(acc[j]);
  }
  __syncthreads();   // makes tid0's cminus write safely visible below

  // ---- V = g1 @ W2 via wave shuffles; contrib -> cbuf ----
  {
    float V[8] = {0,0,0,0,0,0,0,0};
    int klane = (k & 7) << 3;
    for(int ss = 0; ss < 8; ++ss){
      #pragma unroll
      for(int hh = 0; hh < 16; ++hh){
        float gv = __shfl(gg[hh], klane + ss, 64);
        int h = ss*16 + hh;
        #pragma unroll
        for(int j = 0; j < 8; ++j) V[j] = fmaf(gv, w2s[h*64 + s*8 + j], V[j]);
      }
    }
    const float4* l4 = (const float4*)(linG + ((size_t)i*Kk + k)*Cc) + s*2;
    float4 l0 = l4[0], l1 = l4[1];
    float lv[8] = {l0.x,l0.y,l0.z,l0.w,l1.x,l1.y,l1.z,l1.w};
    float mul = (cminus && quS[k] && nbS[k] != -1) ? 1.f : 0.f;
    #pragma unroll
    for(int j = 0; j < 8; ++j) cbuf[k][s*8 + j] = fmaf(mul, V[j], lv[j]);
  }
  __syncthreads();

  // ---- leader aggregation + RMW into out ----
  if(tid < Kk){
    int lead = 1;
    for(int kk = 0; kk < tid; ++kk) if(nwS[kk] == nwS[tid]) lead = 0;
    leadS[tid] = lead;
  }
  __syncthreads();
  if(leadS[k]){
    int col = nwS[k];
    float tot[8] = {0,0,0,0,0,0,0,0};
    for(int kk = 0; kk < Kk; ++kk){
      if(nwS[kk] == col){
        #pragma unroll
        for(int j = 0; j < 8; ++j) tot[j] += cbuf[kk][s*8 + j];
      }
    }
    size_t base = ((size_t)i*Nn + col)*Cc + s*8;
    const float4* pv = (const float4*)(pair + base);
    float4 p0 = pv[0], p1 = pv[1];
    float4 o0 = make_float4(p0.x+tot[0], p0.y+tot[1], p0.z+tot[2], p0.w+tot[3]);
    float4 o1 = make_float4(p1.x+tot[4], p1.y+tot[5], p1.z+tot[6], p1.w+tot[7]);
    float4* ov = (float4*)(out + base);
    ov[0] = o0; ov[1] = o1;
  }
}

// ---------------------------------------------------------------------------
extern "C" void kernel_launch(void* const* d_in, const int* in_sizes, int n_in,
                              void* d_out, int out_size, void* d_ws, size_t ws_size,
                              hipStream_t stream){
  (void)in_sizes; (void)n_in; (void)out_size; (void)ws_size;
  const float* local       = (const float*)d_in[0];
  const float* pair        = (const float*)d_in[1];
  const float* pair_update = (const float*)d_in[2];
  const int*   neighbours  = (const int*)d_in[3];
  const int*   mask        = (const int*)d_in[4];
  const float* Wa          = (const float*)d_in[5];
  const float* Wb          = (const float*)d_in[6];
  const float* ln_g        = (const float*)d_in[7];
  const float* ln_b        = (const float*)d_in[8];
  const float* W_aug       = (const float*)d_in[9];
  const float* W_lin       = (const float*)d_in[10];
  const float* W_left      = (const float*)d_in[11];
  const float* b_left      = (const float*)d_in[12];
  const float* W_right     = (const float*)d_in[13];
  const float* b_right     = (const float*)d_in[14];
  const float* W1          = (const float*)d_in[15];
  const float* W2          = (const float*)d_in[16];
  const float* W_int       = (const float*)d_in[17];
  const float* b_int       = (const float*)d_in[18];

  float* ws    = (float*)d_ws;
  float* A     = ws;                   // 65536 f32
  float* B     = ws + 65536;           // 65536
  float* inter = ws + 131072;          // 65536
  float* r1023 = ws + 196608;          // 1024
  int*   qpart = (int*)(ws + 197632);  // 32 ints
  float* hG    = ws + 197664;          // 1,048,576  [N,K,32]
  float* linG  = ws + 1246240;         // 2,097,152  [N,K,64]

  k0<<<dim3(Nn), dim3(64), 0, stream>>>(local, Wa, Wb, W_int, b_int, A, B, inter);
  k1<<<dim3(1), dim3(256), 0, stream>>>(pair, pair_update, neighbours, mask,
                                        ln_g, ln_b, W_aug, W_right, b_right,
                                        A, B, r1023, qpart);
  k2a<<<dim3(Nn), dim3(256), 0, stream>>>(pair, pair_update, neighbours,
                                          ln_g, ln_b, W_aug, W_lin, W_left, b_left,
                                          A, B, inter, r1023, hG, linG);
  kcopy<<<dim3(8192), dim3(256), 0, stream>>>((const uint4*)pair, (uint4*)d_out,
                                              (Nn*Nn*Cc*4)/16);
  k2b<<<dim3(Nn), dim3(256), 0, stream>>>(pair, neighbours, W1, W2, hG, linG,
                                          qpart, (float*)d_out);
}

// Round 3
// 546.780 us; speedup vs baseline: 1.0460x; 1.0460x over previous
//
#include <hip/hip_runtime.h>
#include <hip/hip_bf16.h>

// Problem constants (N, K, C, CL, H fixed by the reference)
constexpr int Nn  = 1024;
constexpr int Kk  = 32;
constexpr int Cc  = 64;
constexpr int CLl = 128;

typedef unsigned int   u32;
typedef unsigned short u16;

__device__ __forceinline__ float gelu_tanh(float v){
  float c = 0.7978845608028654f*(v + 0.044715f*v*v*v);
  return 0.5f*v*(1.f + tanhf(c));
}
__device__ __forceinline__ float bflo(u32 u){ return __uint_as_float(u<<16); }
__device__ __forceinline__ float bfhi(u32 u){ return __uint_as_float(u & 0xffff0000u); }
__device__ __forceinline__ u32 pack_bf(float a, float b){
  u32 xa = __float_as_uint(a), xb = __float_as_uint(b);
  u32 ra = (xa + 0x7fffu + ((xa>>16)&1u)) >> 16;
  u32 rb = (xb + 0x7fffu + ((xb>>16)&1u)) >> 16;
  return ra | (rb<<16);
}

// ---------------------------------------------------------------------------
// K0: A = local@Wa, B = local@Wb, inter = local@W_int + b_int  (all [N,64] f32)
// ---------------------------------------------------------------------------
__global__ __launch_bounds__(64) void k0(
    const float* __restrict__ local, const float* __restrict__ Wa,
    const float* __restrict__ Wb, const float* __restrict__ Wint,
    const float* __restrict__ b_int,
    float* __restrict__ A, float* __restrict__ B, float* __restrict__ inter){
  int i = blockIdx.x;
  int c = threadIdx.x;              // 0..63
  __shared__ float l[CLl];
  l[c]      = local[i*CLl + c];
  l[c + 64] = local[i*CLl + 64 + c];
  __syncthreads();
  float a = 0.f, b = 0.f, t = 0.f;
  #pragma unroll 4
  for(int d = 0; d < CLl; ++d){
    float ld = l[d];
    a = fmaf(ld, Wa[d*Cc + c], a);
    b = fmaf(ld, Wb[d*Cc + c], b);
    t = fmaf(ld, Wint[d*Cc + c], t);
  }
  A[i*Cc + c] = a;
  B[i*Cc + c] = b;
  inter[i*Cc + c] = t + b_int[c];
}

// ---------------------------------------------------------------------------
// K1: r1023[k][x] = (lp_row1023 @ W_right + b_right)[x],  qpart[k]
// Single block, 256 threads (8 threads per slot k).  (f32 weights — tiny kernel)
// ---------------------------------------------------------------------------
__global__ __launch_bounds__(256) void k1(
    const float* __restrict__ pair, const float* __restrict__ pair_update,
    const int* __restrict__ neigh, const int* __restrict__ mask,
    const float* __restrict__ ln_g, const float* __restrict__ ln_b,
    const float* __restrict__ W_aug, const float* __restrict__ W_right,
    const float* __restrict__ b_right,
    const float* __restrict__ A, const float* __restrict__ B,
    float* __restrict__ r1023, int* __restrict__ qpart){
  const int i = Nn - 1;
  __shared__ float wA[4096];
  __shared__ float wR[2048];
  __shared__ float p [Kk][68];
  __shared__ float pu[Kk][68];
  __shared__ float lp[Kk][68];
  __shared__ int   nwS[Kk];
  __shared__ float ssum[Kk][9], ssq[Kk][9], stats[Kk][2];
  int tid = threadIdx.x;
  for(int idx = tid; idx < 4096; idx += 256) wA[idx] = W_aug[idx];
  for(int idx = tid; idx < 2048; idx += 256) wR[idx] = W_right[idx];
  if(tid < Kk){
    int n = neigh[i*Kk + tid];
    nwS[tid] = (n < 0) ? n + Nn : n;
    qpart[tid] = (n != -1 && mask[n] != 0) ? 1 : 0;
  }
  __syncthreads();
  int k = tid >> 3, s = tid & 7;
  {
    const float* prow = pair + ((size_t)i*Nn + nwS[k])*Cc + s*8;
    const float* pur  = pair_update + ((size_t)i*Kk + k)*Cc + s*8;
    const float* Ar = A + i*Cc + s*8;
    const float* Br = B + (size_t)nwS[k]*Cc + s*8;
    float ps = 0.f, ps2 = 0.f;
    for(int j = 0; j < 8; ++j){
      float v = prow[j];
      p[k][s*8 + j] = v; ps += v; ps2 += v*v;
      pu[k][s*8 + j] = pur[j] + Ar[j] + Br[j];
    }
    ssum[k][s] = ps; ssq[k][s] = ps2;
  }
  __syncthreads();
  if(s == 0){
    float m = 0.f, q = 0.f;
    for(int j = 0; j < 8; ++j){ m += ssum[k][j]; q += ssq[k][j]; }
    m *= (1.f/64.f); q *= (1.f/64.f);
    float var = fmaxf(q - m*m, 0.f);
    stats[k][0] = m; stats[k][1] = rsqrtf(var + 1e-5f);
  }
  __syncthreads();
  {
    float m = stats[k][0], r = stats[k][1];
    float acc[8];
    #pragma unroll
    for(int j = 0; j < 8; ++j){
      int c = s*8 + j;
      acc[j] = (p[k][c] - m)*r*ln_g[c] + ln_b[c];
    }
    for(int d = 0; d < 64; ++d){
      float pd = pu[k][d];
      #pragma unroll
      for(int j = 0; j < 8; ++j) acc[j] = fmaf(pd, wA[d*64 + s*8 + j], acc[j]);
    }
    #pragma unroll
    for(int j = 0; j < 8; ++j) lp[k][s*8 + j] = acc[j];
  }
  __syncthreads();
  {
    float acc[4] = {0.f,0.f,0.f,0.f};
    for(int d = 0; d < 64; ++d){
      float ld = lp[k][d];
      #pragma unroll
      for(int j = 0; j < 4; ++j) acc[j] = fmaf(ld, wR[d*32 + s*4 + j], acc[j]);
    }
    #pragma unroll
    for(int j = 0; j < 4; ++j)
      r1023[k*32 + s*4 + j] = acc[j] + b_right[s*4 + j];
  }
}

// ---------------------------------------------------------------------------
// K2a: per row i — gather + LN + lp = LN*g+b + pu@W_aug;
//      lin[i,k,:] = lp@W_lin + inter[i,:];  h[i,k,:] = lp@W_left + b_left + r1023[k]
// Weights live in LDS as PACKED BF16 (halves LDS bytes; accuracy headroom huge).
// Slot-pairing: thread t -> (kq = t>>4 in 0..15, s = t&15); handles slots
// {kq, kq+16}, cols s*4..s*4+3 (W_left cols s*2..s*2+1).
// ---------------------------------------------------------------------------
__global__ __launch_bounds__(256) void k2a(
    const float* __restrict__ pair, const float* __restrict__ pair_update,
    const int* __restrict__ neigh,
    const float* __restrict__ ln_g, const float* __restrict__ ln_b,
    const float* __restrict__ W_aug, const float* __restrict__ W_lin,
    const float* __restrict__ W_left, const float* __restrict__ b_left,
    const float* __restrict__ A, const float* __restrict__ B,
    const float* __restrict__ inter, const float* __restrict__ r1023,
    float* __restrict__ hG, float* __restrict__ linG){
  __shared__ u32 wbA[2048];           // W_aug  [64][64] bf16-packed (pairs along cols)
  __shared__ u32 wbL[2048];           // W_lin  [64][64] bf16-packed
  __shared__ u32 wbF[1024];           // W_left [64][32] bf16-packed
  __shared__ float pbuf [Kk][68];     // pair raw -> (in-place) lp
  __shared__ float pubuf[Kk][68];     // pu
  __shared__ float AiS[64], InS[64], lgS[64], lbS[64];
  __shared__ float ssum[Kk][9], ssq[Kk][9], stats[Kk][2];
  __shared__ int nwS[Kk];

  int i   = blockIdx.x;
  int tid = threadIdx.x;

  // ---- stage weights (pack f32 -> bf16 pairs) ----
  for(int idx = tid; idx < 2048; idx += 256){
    const float2 wa = *(const float2*)(W_aug + idx*2);
    wbA[idx] = pack_bf(wa.x, wa.y);
    const float2 wl = *(const float2*)(W_lin + idx*2);
    wbL[idx] = pack_bf(wl.x, wl.y);
  }
  for(int idx = tid; idx < 1024; idx += 256){
    const float2 wf = *(const float2*)(W_left + idx*2);
    wbF[idx] = pack_bf(wf.x, wf.y);
  }
  if(tid < Kk){
    int n = neigh[i*Kk + tid];
    nwS[tid] = (n < 0) ? n + Nn : n;
  }
  if(tid < 64){
    AiS[tid] = A[i*Cc + tid];
    InS[tid] = inter[i*Cc + tid];
    lgS[tid] = ln_g[tid];
    lbS[tid] = ln_b[tid];
  }
  __syncthreads();

  // ---- gather pair row segments + build pu (mapping: k8 = tid>>3, s8 = tid&7) ----
  {
    int k8 = tid >> 3, s8 = tid & 7;
    const float4* p4 = (const float4*)(pair + ((size_t)i*Nn + nwS[k8])*Cc) + s8*2;
    float4 p0 = p4[0], p1 = p4[1];
    const float4* u4 = (const float4*)(pair_update + ((size_t)i*Kk + k8)*Cc) + s8*2;
    float4 u0 = u4[0], u1 = u4[1];
    const float4* Br = (const float4*)(B + (size_t)nwS[k8]*Cc) + s8*2;
    float4 b0 = Br[0], b1 = Br[1];
    float pf[8] = {p0.x,p0.y,p0.z,p0.w,p1.x,p1.y,p1.z,p1.w};
    float uf[8] = {u0.x,u0.y,u0.z,u0.w,u1.x,u1.y,u1.z,u1.w};
    float bv[8] = {b0.x,b0.y,b0.z,b0.w,b1.x,b1.y,b1.z,b1.w};
    float ps = 0.f, ps2 = 0.f;
    #pragma unroll
    for(int j = 0; j < 8; ++j){
      float v = pf[j];
      pbuf[k8][s8*8 + j] = v; ps += v; ps2 += v*v;
      pubuf[k8][s8*8 + j] = uf[j] + AiS[s8*8 + j] + bv[j];
    }
    ssum[k8][s8] = ps; ssq[k8][s8] = ps2;
  }
  __syncthreads();

  // ---- LN stats ----
  if((tid & 7) == 0){
    int k8 = tid >> 3;
    float m = 0.f, q = 0.f;
    for(int j = 0; j < 8; ++j){ m += ssum[k8][j]; q += ssq[k8][j]; }
    m *= (1.f/64.f); q *= (1.f/64.f);
    float var = fmaxf(q - m*m, 0.f);
    stats[k8][0] = m; stats[k8][1] = rsqrtf(var + 1e-5f);
  }
  __syncthreads();

  int kq = tid >> 4;          // 0..15 -> slots kq, kq+16
  int s  = tid & 15;          // col group: c0 = s*4
  int k0 = kq, k1i = kq + 16;
  int c0 = s*4;

  // ---- lp = LN(pair)*g+b + pu @ W_aug  (2 slots per thread) ----
  float a0[4], a1[4];
  {
    float m0 = stats[k0][0], r0 = stats[k0][1];
    float m1 = stats[k1i][0], r1 = stats[k1i][1];
    #pragma unroll
    for(int j = 0; j < 4; ++j){
      int c = c0 + j;
      a0[j] = (pbuf[k0][c]  - m0)*r0*lgS[c] + lbS[c];
      a1[j] = (pbuf[k1i][c] - m1)*r1*lgS[c] + lbS[c];
    }
    #pragma unroll 4
    for(int d = 0; d < 64; ++d){
      uint2 wv = *(const uint2*)&wbA[d*32 + s*2];
      float w0 = bflo(wv.x), w1 = bfhi(wv.x), w2 = bflo(wv.y), w3 = bfhi(wv.y);
      float p0 = pubuf[k0][d], p1 = pubuf[k1i][d];
      a0[0] = fmaf(p0, w0, a0[0]); a0[1] = fmaf(p0, w1, a0[1]);
      a0[2] = fmaf(p0, w2, a0[2]); a0[3] = fmaf(p0, w3, a0[3]);
      a1[0] = fmaf(p1, w0, a1[0]); a1[1] = fmaf(p1, w1, a1[1]);
      a1[2] = fmaf(p1, w2, a1[2]); a1[3] = fmaf(p1, w3, a1[3]);
    }
  }
  __syncthreads();    // pbuf cols already consumed by owners; safe to overwrite
  {
    #pragma unroll
    for(int j = 0; j < 4; ++j){ pbuf[k0][c0 + j] = a0[j]; pbuf[k1i][c0 + j] = a1[j]; }
  }
  __syncthreads();

  // ---- lin = lp@W_lin + inter;  h = lp@W_left + b_left + r1023 ----
  {
    float L0[4] = {0,0,0,0}, L1[4] = {0,0,0,0};
    float X0[2] = {0,0},     X1[2] = {0,0};
    #pragma unroll 4
    for(int d = 0; d < 64; ++d){
      float p0 = pbuf[k0][d], p1 = pbuf[k1i][d];
      uint2 wv = *(const uint2*)&wbL[d*32 + s*2];
      float w0 = bflo(wv.x), w1 = bfhi(wv.x), w2 = bflo(wv.y), w3 = bfhi(wv.y);
      L0[0] = fmaf(p0, w0, L0[0]); L0[1] = fmaf(p0, w1, L0[1]);
      L0[2] = fmaf(p0, w2, L0[2]); L0[3] = fmaf(p0, w3, L0[3]);
      L1[0] = fmaf(p1, w0, L1[0]); L1[1] = fmaf(p1, w1, L1[1]);
      L1[2] = fmaf(p1, w2, L1[2]); L1[3] = fmaf(p1, w3, L1[3]);
      u32 wf = wbF[d*16 + s];
      float f0 = bflo(wf), f1 = bfhi(wf);
      X0[0] = fmaf(p0, f0, X0[0]); X0[1] = fmaf(p0, f1, X0[1]);
      X1[0] = fmaf(p1, f0, X1[0]); X1[1] = fmaf(p1, f1, X1[1]);
    }
    float4 o0 = make_float4(L0[0]+InS[c0], L0[1]+InS[c0+1], L0[2]+InS[c0+2], L0[3]+InS[c0+3]);
    float4 o1 = make_float4(L1[0]+InS[c0], L1[1]+InS[c0+1], L1[2]+InS[c0+2], L1[3]+InS[c0+3]);
    *(float4*)(linG + ((size_t)i*Kk + k0 )*Cc + c0) = o0;
    *(float4*)(linG + ((size_t)i*Kk + k1i)*Cc + c0) = o1;
    int x0 = s*2;
    float2 bl = *(const float2*)(b_left + x0);
    float2 rA = *(const float2*)(r1023 + k0*32  + x0);
    float2 rB = *(const float2*)(r1023 + k1i*32 + x0);
    float2 h0 = make_float2(X0[0] + bl.x + rA.x, X0[1] + bl.y + rA.y);
    float2 h1 = make_float2(X1[0] + bl.x + rB.x, X1[1] + bl.y + rB.y);
    *(float2*)(hG + ((size_t)i*Kk + k0 )*32 + x0) = h0;
    *(float2*)(hG + ((size_t)i*Kk + k1i)*32 + x0) = h1;
  }
}

// ---------------------------------------------------------------------------
// KFuse: per row i — copy full pair row to out, compute V = gelu(h@W1)@W2,
// contrib = mul*V + lin, leader dedup-aggregate, overwrite touched columns.
// Weights in LDS as packed bf16.
// ---------------------------------------------------------------------------
__global__ __launch_bounds__(256) void kfuse(
    const float* __restrict__ pair, const int* __restrict__ neigh,
    const float* __restrict__ W1, const float* __restrict__ W2,
    const float* __restrict__ hG, const float* __restrict__ linG,
    const int* __restrict__ qpart,
    float* __restrict__ out){
  __shared__ u32 w1b[2048];           // W1 [32][128] bf16-packed
  __shared__ u32 w2b[4096];           // W2 [128][64] bf16-packed
  __shared__ float hbuf[Kk][36];
  __shared__ float cbuf[Kk][68];      // contrib
  __shared__ int nbS[Kk], nwS[Kk], quS[Kk], leadS[Kk];
  __shared__ int cminus;

  int i   = blockIdx.x;
  int tid = threadIdx.x;

  // ---- bulk row copy: out[i,:] = pair[i,:]  (16384 float4s) ----
  {
    const float4* src = (const float4*)(pair + (size_t)i*Nn*Cc);
    float4*       dst = (float4*)(out + (size_t)i*Nn*Cc);
    #pragma unroll 4
    for(int idx = tid; idx < 16384; idx += 256) dst[idx] = src[idx];
  }

  // ---- stage weights + h + per-row scalars ----
  for(int idx = tid; idx < 2048; idx += 256){
    const float2 w1 = *(const float2*)(W1 + idx*2);
    w1b[idx] = pack_bf(w1.x, w1.y);
    const float2 wa = *(const float2*)(W2 + idx*2);
    w2b[idx] = pack_bf(wa.x, wa.y);
    const float2 wb2 = *(const float2*)(W2 + 4096 + idx*2);
    w2b[2048 + idx] = pack_bf(wb2.x, wb2.y);
  }
  for(int idx = tid; idx < 1024; idx += 256)
    hbuf[idx >> 5][idx & 31] = hG[(size_t)i*1024 + idx];
  if(tid < Kk){
    int n = neigh[i*Kk + tid];
    nbS[tid] = n;
    nwS[tid] = (n < 0) ? n + Nn : n;
    quS[tid] = qpart[tid];
  }
  __syncthreads();
  if(tid == 0){
    int c = 0;
    for(int kk = 0; kk < Kk; ++kk) c |= (nbS[kk] == -1);
    cminus = c;
  }

  int kq = tid >> 4;          // 0..15 -> slots kq, kq+16
  int s  = tid & 15;

  // ---- g1 = gelu(h @ W1): thread holds h-cols s*8..s*8+7 for 2 slots ----
  float g0[8], g1v[8];
  {
    float A0[8], A1[8];
    #pragma unroll
    for(int j = 0; j < 8; ++j){ A0[j] = 0.f; A1[j] = 0.f; }
    #pragma unroll 2
    for(int x = 0; x < 32; ++x){
      float h0 = hbuf[kq][x], h1 = hbuf[kq+16][x];
      uint4 wv = *(const uint4*)&w1b[x*64 + s*4];
      float w[8] = {bflo(wv.x),bfhi(wv.x),bflo(wv.y),bfhi(wv.y),
                    bflo(wv.z),bfhi(wv.z),bflo(wv.w),bfhi(wv.w)};
      #pragma unroll
      for(int j = 0; j < 8; ++j){
        A0[j] = fmaf(h0, w[j], A0[j]);
        A1[j] = fmaf(h1, w[j], A1[j]);
      }
    }
    #pragma unroll
    for(int j = 0; j < 8; ++j){ g0[j] = gelu_tanh(A0[j]); g1v[j] = gelu_tanh(A1[j]); }
  }
  __syncthreads();   // cminus visibility

  // ---- V = g1 @ W2 via wave shuffles; contrib -> cbuf (cols s*4..s*4+3) ----
  {
    float V0[4] = {0,0,0,0}, V1[4] = {0,0,0,0};
    int lbase = (kq & 3) << 4;       // lane block of this kq within the wave
    for(int hb = 0; hb < 16; ++hb){
      int src = lbase | hb;          // lane holding h-cols hb*8..hb*8+7
      #pragma unroll
      for(int hj = 0; hj < 8; ++hj){
        float gA = __shfl(g0[hj],  src, 64);
        float gB = __shfl(g1v[hj], src, 64);
        int h = hb*8 + hj;
        uint2 wv = *(const uint2*)&w2b[h*32 + s*2];
        float w0 = bflo(wv.x), w1 = bfhi(wv.x), w2 = bflo(wv.y), w3 = bfhi(wv.y);
        V0[0] = fmaf(gA, w0, V0[0]); V0[1] = fmaf(gA, w1, V0[1]);
        V0[2] = fmaf(gA, w2, V0[2]); V0[3] = fmaf(gA, w3, V0[3]);
        V1[0] = fmaf(gB, w0, V1[0]); V1[1] = fmaf(gB, w1, V1[1]);
        V1[2] = fmaf(gB, w2, V1[2]); V1[3] = fmaf(gB, w3, V1[3]);
      }
    }
    int c0 = s*4;
    float4 l0 = *(const float4*)(linG + ((size_t)i*Kk + kq     )*Cc + c0);
    float4 l1 = *(const float4*)(linG + ((size_t)i*Kk + kq + 16)*Cc + c0);
    float mul0 = (cminus && quS[kq]      && nbS[kq]      != -1) ? 1.f : 0.f;
    float mul1 = (cminus && quS[kq + 16] && nbS[kq + 16] != -1) ? 1.f : 0.f;
    cbuf[kq][c0+0] = fmaf(mul0, V0[0], l0.x);
    cbuf[kq][c0+1] = fmaf(mul0, V0[1], l0.y);
    cbuf[kq][c0+2] = fmaf(mul0, V0[2], l0.z);
    cbuf[kq][c0+3] = fmaf(mul0, V0[3], l0.w);
    cbuf[kq+16][c0+0] = fmaf(mul1, V1[0], l1.x);
    cbuf[kq+16][c0+1] = fmaf(mul1, V1[1], l1.y);
    cbuf[kq+16][c0+2] = fmaf(mul1, V1[2], l1.z);
    cbuf[kq+16][c0+3] = fmaf(mul1, V1[3], l1.w);
  }
  __syncthreads();

  // ---- leader dedup + aggregate + overwrite touched columns ----
  if(tid < Kk){
    int lead = 1;
    for(int kk = 0; kk < tid; ++kk) if(nwS[kk] == nwS[tid]) lead = 0;
    leadS[tid] = lead;
  }
  __syncthreads();
  {
    int k8 = tid >> 3, s8 = tid & 7;
    if(leadS[k8]){
      int col = nwS[k8];
      float tot[8] = {0,0,0,0,0,0,0,0};
      for(int kk = 0; kk < Kk; ++kk){
        if(nwS[kk] == col){
          #pragma unroll
          for(int j = 0; j < 8; ++j) tot[j] += cbuf[kk][s8*8 + j];
        }
      }
      size_t base = ((size_t)i*Nn + col)*Cc + s8*8;
      const float4* pv = (const float4*)(pair + base);
      float4 p0 = pv[0], p1 = pv[1];
      float4 o0 = make_float4(p0.x+tot[0], p0.y+tot[1], p0.z+tot[2], p0.w+tot[3]);
      float4 o1 = make_float4(p1.x+tot[4], p1.y+tot[5], p1.z+tot[6], p1.w+tot[7]);
      float4* ov = (float4*)(out + base);
      ov[0] = o0; ov[1] = o1;
    }
  }
}

// ---------------------------------------------------------------------------
extern "C" void kernel_launch(void* const* d_in, const int* in_sizes, int n_in,
                              void* d_out, int out_size, void* d_ws, size_t ws_size,
                              hipStream_t stream){
  (void)in_sizes; (void)n_in; (void)out_size; (void)ws_size;
  const float* local       = (const float*)d_in[0];
  const float* pair        = (const float*)d_in[1];
  const float* pair_update = (const float*)d_in[2];
  const int*   neighbours  = (const int*)d_in[3];
  const int*   mask        = (const int*)d_in[4];
  const float* Wa          = (const float*)d_in[5];
  const float* Wb          = (const float*)d_in[6];
  const float* ln_g        = (const float*)d_in[7];
  const float* ln_b        = (const float*)d_in[8];
  const float* W_aug       = (const float*)d_in[9];
  const float* W_lin       = (const float*)d_in[10];
  const float* W_left      = (const float*)d_in[11];
  const float* b_left      = (const float*)d_in[12];
  const float* W_right     = (const float*)d_in[13];
  const float* b_right     = (const float*)d_in[14];
  const float* W1          = (const float*)d_in[15];
  const float* W2          = (const float*)d_in[16];
  const float* W_int       = (const float*)d_in[17];
  const float* b_int       = (const float*)d_in[18];

  float* ws    = (float*)d_ws;
  float* A     = ws;                   // 65536 f32
  float* B     = ws + 65536;           // 65536
  float* inter = ws + 131072;          // 65536
  float* r1023 = ws + 196608;          // 1024
  int*   qpart = (int*)(ws + 197632);  // 32 ints
  float* hG    = ws + 197664;          // 1,048,576  [N,K,32]
  float* linG  = ws + 1246240;         // 2,097,152  [N,K,64]

  k0<<<dim3(Nn), dim3(64), 0, stream>>>(local, Wa, Wb, W_int, b_int, A, B, inter);
  k1<<<dim3(1), dim3(256), 0, stream>>>(pair, pair_update, neighbours, mask,
                                        ln_g, ln_b, W_aug, W_right, b_right,
                                        A, B, r1023, qpart);
  k2a<<<dim3(Nn), dim3(256), 0, stream>>>(pair, pair_update, neighbours,
                                          ln_g, ln_b, W_aug, W_lin, W_left, b_left,
                                          A, B, inter, r1023, hG, linG);
  kfuse<<<dim3(Nn), dim3(256), 0, stream>>>(pair, neighbours, W1, W2, hG, linG,
                                            qpart, (float*)d_out);
}